// Round 12
// baseline (191.715 us; speedup 1.0000x reference)
//
#include <hip/hip_runtime.h>
#include <math.h>

#define N_NODES 100000
#define N_EDGES 1600000
#define NBUK 782          // dst>>7 -> 0..781 (128 nodes per bucket)
#define BCAP 2600         // entries per bucket region (mean 2046)
#define BINCHUNK 4096     // edges per k_bin block (256 thr x 16)

typedef unsigned short u16;
typedef u16 u16x4 __attribute__((ext_vector_type(4)));
typedef u16 u16x8 __attribute__((ext_vector_type(8)));
typedef short s16x8 __attribute__((ext_vector_type(8)));
typedef float f32x4 __attribute__((ext_vector_type(4)));

__device__ __forceinline__ float bf2f(u16 u) {
    union { unsigned i; float f; } v; v.i = ((unsigned)u) << 16; return v.f;
}
__device__ __forceinline__ u16 f2bf(float f) {
    union { float f; unsigned i; } v; v.f = f;
    return (u16)((v.i + 0x7FFFu + ((v.i >> 16) & 1u)) >> 16);  // RNE
}

// ---------------------------------------------------------------- binning ---
__global__ __launch_bounds__(256) void k_bin(const int* __restrict__ src,
                                             const int* __restrict__ dst,
                                             int* bucketCursor,
                                             unsigned int* __restrict__ bins) {
    __shared__ int lcnt[NBUK];
    __shared__ int lbase[NBUK];
    const int t = threadIdx.x;
    for (int i = t; i < NBUK; i += 256) lcnt[i] = 0;
    __syncthreads();

    const int e0 = blockIdx.x * BINCHUNK + t * 16;
    int4 s4[4], d4[4];
    int bkt[16], rnk[16];
    const bool valid = e0 < N_EDGES;   // N_EDGES % 16 == 0
    if (valid) {
        #pragma unroll
        for (int k = 0; k < 4; ++k) {
            s4[k] = *(const int4*)(src + e0 + 4 * k);
            d4[k] = *(const int4*)(dst + e0 + 4 * k);
        }
        #pragma unroll
        for (int k = 0; k < 4; ++k) {
            int dd[4] = { d4[k].x, d4[k].y, d4[k].z, d4[k].w };
            #pragma unroll
            for (int j = 0; j < 4; ++j) {
                int b = dd[j] >> 7;
                bkt[4 * k + j] = b;
                rnk[4 * k + j] = atomicAdd(&lcnt[b], 1);
            }
        }
    }
    __syncthreads();
    for (int i = t; i < NBUK; i += 256)
        if (lcnt[i] > 0) lbase[i] = atomicAdd(&bucketCursor[i], lcnt[i]);
    __syncthreads();
    if (valid) {
        #pragma unroll
        for (int k = 0; k < 4; ++k) {
            int ss[4] = { s4[k].x, s4[k].y, s4[k].z, s4[k].w };
            int dd[4] = { d4[k].x, d4[k].y, d4[k].z, d4[k].w };
            #pragma unroll
            for (int j = 0; j < 4; ++j) {
                int i = 4 * k + j;
                unsigned w = ((unsigned)(dd[j] & 127) << 17) | (unsigned)ss[j];
                bins[(size_t)bkt[i] * BCAP + lbase[bkt[i]] + rnk[i]] = w;
            }
        }
    }
}

// ------------------------------------------------- bucket-total scan (1 wg) -
__global__ __launch_bounds__(256) void k_bscan(const int* __restrict__ bucketCursor,
                                               int* __restrict__ gBase,
                                               int* __restrict__ row_start) {
    __shared__ int sd[256];
    const int t = threadIdx.x;
    const int idx0 = t * 4;
    int v0 = (idx0 + 0 < NBUK) ? bucketCursor[idx0 + 0] : 0;
    int v1 = (idx0 + 1 < NBUK) ? bucketCursor[idx0 + 1] : 0;
    int v2 = (idx0 + 2 < NBUK) ? bucketCursor[idx0 + 2] : 0;
    int v3 = (idx0 + 3 < NBUK) ? bucketCursor[idx0 + 3] : 0;
    int s0 = v0, s1 = s0 + v1, s2 = s1 + v2, s3 = s2 + v3;
    sd[t] = s3;
    __syncthreads();
    #pragma unroll
    for (int off = 1; off < 256; off <<= 1) {
        int x = (t >= off) ? sd[t - off] : 0;
        __syncthreads();
        sd[t] += x;
        __syncthreads();
    }
    int excl = (t > 0) ? sd[t - 1] : 0;
    if (idx0 + 0 < NBUK) gBase[idx0 + 0] = excl;
    if (idx0 + 1 < NBUK) gBase[idx0 + 1] = excl + s0;
    if (idx0 + 2 < NBUK) gBase[idx0 + 2] = excl + s1;
    if (idx0 + 3 < NBUK) gBase[idx0 + 3] = excl + s2;
    if (t == 0) row_start[N_NODES] = N_EDGES;
}

// ------------------------------------------- per-bucket CSR build (128) -----
__global__ __launch_bounds__(256) void k_build(const unsigned int* __restrict__ bins,
                                               const int* __restrict__ bucketCursor,
                                               const int* __restrict__ gBase,
                                               int* __restrict__ row_start,
                                               float* __restrict__ dinv,
                                               int* __restrict__ csr_src) {
    __shared__ int cnt[128];
    __shared__ int ps[128];
    __shared__ int cur[128];
    const int b = blockIdx.x;
    const int t = threadIdx.x;
    const int bcnt = bucketCursor[b];
    const int gb = gBase[b];
    const unsigned int* mybins = bins + (size_t)b * BCAP;

    if (t < 128) cnt[t] = 0;
    __syncthreads();
    for (int i = t; i < bcnt; i += 256)
        atomicAdd(&cnt[mybins[i] >> 17], 1);
    __syncthreads();
    if (t < 128) ps[t] = cnt[t];
    __syncthreads();
    #pragma unroll
    for (int off = 1; off < 128; off <<= 1) {
        int x = (t >= off && t < 128) ? ps[t - off] : 0;
        __syncthreads();
        if (t < 128) ps[t] += x;
        __syncthreads();
    }
    if (t < 128) {
        int excl = (t > 0) ? ps[t - 1] : 0;
        cur[t] = excl;
        int node = (b << 7) + t;
        if (node < N_NODES) {
            row_start[node] = gb + excl;
            dinv[node] = rsqrtf((float)(cnt[t] + 1));
        }
    }
    __syncthreads();
    for (int i = t; i < bcnt; i += 256) {
        unsigned w = mybins[i];
        int dl = w >> 17;
        int s = (int)(w & 0x1FFFFu);
        int p = atomicAdd(&cur[dl], 1);
        csr_src[gb + p] = s;
    }
}

// --------------------------------------- W pre-split (transposed+swizzled) --
// w1pre: [hi 16KB][lo 16KB]  byte = (c*256 + k*2) ^ ((c&7)<<4)   (c<64,k<128)
// w2pre: [hi 8KB][lo 8KB]    byte = (c*128 + k*2) ^ ((c&7)<<4)   (c<64,k<64)
__global__ __launch_bounds__(256) void k_wsplit(const float* __restrict__ W1,
                                                const float* __restrict__ W2,
                                                u16* __restrict__ w1pre,
                                                u16* __restrict__ w2pre) {
    const int t = threadIdx.x;
    #pragma unroll
    for (int i = 0; i < 32; ++i) {
        int e = i * 256 + t;           // e = k*64 + c
        int k = e >> 6, c = e & 63;
        float f = W1[e];
        u16 h = f2bf(f);
        u16 l = f2bf(f - bf2f(h));
        int byte = (c * 256 + k * 2) ^ ((c & 7) << 4);
        *(u16*)((char*)w1pre + byte) = h;
        *(u16*)((char*)w1pre + 16384 + byte) = l;
    }
    #pragma unroll
    for (int i = 0; i < 16; ++i) {
        int e = i * 256 + t;
        int k = e >> 6, c = e & 63;
        float f = W2[e];
        u16 h = f2bf(f);
        u16 l = f2bf(f - bf2f(h));
        int byte = (c * 128 + k * 2) ^ ((c & 7) << 4);
        *(u16*)((char*)w2pre + byte) = h;
        *(u16*)((char*)w2pre + 8192 + byte) = l;
    }
}

// ------------------------------------------------------- GEMM1 (MFMA) -------
// C = (x @ W1) * dinv via hi/lo bf16 split; W1 pre-split in w1pre.
__global__ __launch_bounds__(256) void k_gemm1(const float* __restrict__ X,
                                               const u16* __restrict__ w1pre,
                                               const float* __restrict__ dinv,
                                               u16* __restrict__ H) {
    __shared__ u16 sxh[64 * 128];
    __shared__ u16 sxl[64 * 128];
    __shared__ u16 wth[64 * 128];
    __shared__ u16 wtl[64 * 128];
    const int t = threadIdx.x;
    const int blk = blockIdx.x;

    {   // stage x tile: 64 rows x 128 cols fp32 -> hi/lo bf16
        const float4* Xv = (const float4*)X;
        #pragma unroll
        for (int i = 0; i < 8; ++i) {
            int idx = i * 256 + t;
            int row = idx >> 5;
            int k4  = (idx & 31) << 2;
            int grow = blk * 64 + row;
            float4 v = make_float4(0.f, 0.f, 0.f, 0.f);
            if (grow < N_NODES) v = Xv[(size_t)grow * 32 + (idx & 31)];
            float f[4] = { v.x, v.y, v.z, v.w };
            u16x4 hv, lv;
            #pragma unroll
            for (int j = 0; j < 4; ++j) {
                u16 h = f2bf(f[j]);
                hv[j] = h;
                lv[j] = f2bf(f[j] - bf2f(h));
            }
            int byte = (row * 256 + k4 * 2) ^ ((row & 7) << 4);
            *(u16x4*)((char*)sxh + byte) = hv;
            *(u16x4*)((char*)sxl + byte) = lv;
        }
    }
    {   // stage pre-split W1: pure 16B copy (layout already swizzled)
        const u16x8* G = (const u16x8*)w1pre;
        u16x8* Lh = (u16x8*)wth;
        u16x8* Ll = (u16x8*)wtl;
        #pragma unroll
        for (int i = 0; i < 4; ++i) Lh[i * 256 + t] = G[i * 256 + t];
        #pragma unroll
        for (int i = 0; i < 4; ++i) Ll[i * 256 + t] = G[1024 + i * 256 + t];
    }
    __syncthreads();

    const int lane = t & 63;
    const int w    = t >> 6;
    const int l16  = lane & 15;
    const int kg   = lane >> 4;
    f32x4 acc[4];
    #pragma unroll
    for (int nt = 0; nt < 4; ++nt)
        #pragma unroll
        for (int j = 0; j < 4; ++j) acc[nt][j] = 0.f;

    const int arow = w * 16 + l16;
    const int aswz = (arow & 7) << 4;
    #pragma unroll
    for (int kt = 0; kt < 4; ++kt) {
        const int koff = kt * 64 + kg * 16;
        s16x8 ah = *(const s16x8*)((const char*)sxh + ((arow * 256 + koff) ^ aswz));
        s16x8 al = *(const s16x8*)((const char*)sxl + ((arow * 256 + koff) ^ aswz));
        #pragma unroll
        for (int nt = 0; nt < 4; ++nt) {
            const int c = nt * 16 + l16;
            const int wb = (c * 256 + koff) ^ ((c & 7) << 4);
            s16x8 bh = *(const s16x8*)((const char*)wth + wb);
            s16x8 bl = *(const s16x8*)((const char*)wtl + wb);
            acc[nt] = __builtin_amdgcn_mfma_f32_16x16x32_bf16(ah, bh, acc[nt], 0, 0, 0);
            acc[nt] = __builtin_amdgcn_mfma_f32_16x16x32_bf16(ah, bl, acc[nt], 0, 0, 0);
            acc[nt] = __builtin_amdgcn_mfma_f32_16x16x32_bf16(al, bh, acc[nt], 0, 0, 0);
        }
    }
    const int rbase = blk * 64 + w * 16 + kg * 4;
    #pragma unroll
    for (int reg = 0; reg < 4; ++reg) {
        int row = rbase + reg;
        float di = (row < N_NODES) ? dinv[row] : 0.f;
        #pragma unroll
        for (int nt = 0; nt < 4; ++nt)
            __builtin_nontemporal_store(f2bf(acc[nt][reg] * di),
                                        &H[(size_t)row * 64 + nt * 16 + l16]);
    }
}

// ----------------------------- fused aggregate1 + GELU + GEMM2 --------------
// Block = 64 nodes, 4 waves x 16 nodes. Each wave runs the scalar-index
// branchless aggregate per node (r11 structure), writes gelu rows into the
// swizzled LDS A-tile; barrier; MFMA with pre-split W2; nt-store H2.
__global__ __launch_bounds__(256) void k_agg1g2(const u16* __restrict__ hs,
                                                const int* __restrict__ csr_src,
                                                const int* __restrict__ row_start,
                                                const float* __restrict__ dinv,
                                                const float* __restrict__ b1,
                                                const u16* __restrict__ w2pre,
                                                u16* __restrict__ H2) {
    __shared__ u16 sxb[64 * 64];
    __shared__ u16 wth[64 * 64];
    __shared__ u16 wtl[64 * 64];
    const int t = threadIdx.x;
    const int blk = blockIdx.x;
    const int w = t >> 6;
    const int lane = t & 63;

    {   // stage pre-split W2 (16 KB): pure copy
        const u16x8* G = (const u16x8*)w2pre;
        u16x8* Lh = (u16x8*)wth;
        u16x8* Ll = (u16x8*)wtl;
        #pragma unroll
        for (int i = 0; i < 2; ++i) Lh[i * 256 + t] = G[i * 256 + t];
        #pragma unroll
        for (int i = 0; i < 2; ++i) Ll[i * 256 + t] = G[512 + i * 256 + t];
    }

    // ---- aggregate phase ----
    const u16* __restrict__ colp = hs + lane;
    const float bb = b1[lane];
    #pragma unroll 1
    for (int i = 0; i < 16; ++i) {
        const int row = w * 16 + i;
        const int node = blk * 64 + row;          // wave-uniform
        const int byte = (row * 128 + lane * 2) ^ ((row & 7) << 4);
        if (node < N_NODES) {
            const int jS = __builtin_amdgcn_readfirstlane(row_start[node]);
            const int jE = __builtin_amdgcn_readfirstlane(row_start[node + 1]);
            const int deg = jE - jS;
            int raw[32];
            #pragma unroll
            for (int k = 0; k < 32; ++k)
                raw[k] = __builtin_amdgcn_readfirstlane(csr_src[jS + k]);
            float acc = bf2f(colp[(size_t)node << 6]);   // self-loop
            u16 v[32];
            #pragma unroll
            for (int k = 0; k < 32; ++k) {
                int idx = (k < deg) ? raw[k] : N_NODES;
                v[k] = colp[(size_t)(unsigned)idx << 6];
            }
            #pragma unroll
            for (int k = 0; k < 32; ++k) acc += bf2f(v[k]);
            if (deg > 32) {
                for (int j = jS + 32; j < jE; ++j) {
                    int idx = __builtin_amdgcn_readfirstlane(csr_src[j]);
                    acc += bf2f(colp[(size_t)(unsigned)idx << 6]);
                }
            }
            float r = dinv[node] * acc + bb;
            r = 0.5f * r * (1.0f + erff(r * 0.70710678118654752f));
            *(u16*)((char*)sxb + byte) = f2bf(r);
        } else {
            *(u16*)((char*)sxb + byte) = 0;
        }
    }
    __syncthreads();

    // ---- GEMM2 MFMA phase ----
    const int l16 = lane & 15;
    const int kg  = lane >> 4;
    f32x4 acc[4];
    #pragma unroll
    for (int nt = 0; nt < 4; ++nt)
        #pragma unroll
        for (int j = 0; j < 4; ++j) acc[nt][j] = 0.f;

    const int arow = w * 16 + l16;
    const int aswz = (arow & 7) << 4;
    #pragma unroll
    for (int kt = 0; kt < 2; ++kt) {
        const int koff = kt * 64 + kg * 16;
        s16x8 a = *(const s16x8*)((const char*)sxb + ((arow * 128 + koff) ^ aswz));
        #pragma unroll
        for (int nt = 0; nt < 4; ++nt) {
            const int c = nt * 16 + l16;
            const int wb = (c * 128 + koff) ^ ((c & 7) << 4);
            s16x8 bh = *(const s16x8*)((const char*)wth + wb);
            s16x8 bl = *(const s16x8*)((const char*)wtl + wb);
            acc[nt] = __builtin_amdgcn_mfma_f32_16x16x32_bf16(a, bh, acc[nt], 0, 0, 0);
            acc[nt] = __builtin_amdgcn_mfma_f32_16x16x32_bf16(a, bl, acc[nt], 0, 0, 0);
        }
    }
    const int rbase = blk * 64 + w * 16 + kg * 4;
    #pragma unroll
    for (int reg = 0; reg < 4; ++reg) {
        int row = rbase + reg;
        float di = (row < N_NODES) ? dinv[row] : 0.f;
        #pragma unroll
        for (int nt = 0; nt < 4; ++nt)
            __builtin_nontemporal_store(f2bf(acc[nt][reg] * di),
                                        &H2[(size_t)row * 64 + nt * 16 + l16]);
    }
}

// ---------------------------------------------------------------- aggregate -
// Final aggregate (layer 2): one wave per node, scalar-path indices,
// branchless 32-deep gather window (r11 structure). fp32 output.
__global__ __launch_bounds__(256) void k_aggregate2(const u16* __restrict__ hs,
                                                    const int* __restrict__ csr_src,
                                                    const int* __restrict__ row_start,
                                                    const float* __restrict__ dinv,
                                                    const float* __restrict__ b,
                                                    float* __restrict__ out) {
    const int t = threadIdx.x;
    const int lane = t & 63;
    const int node = __builtin_amdgcn_readfirstlane(blockIdx.x * 4 + (t >> 6));
    const int jS = __builtin_amdgcn_readfirstlane(row_start[node]);
    const int jE = __builtin_amdgcn_readfirstlane(row_start[node + 1]);
    const int deg = jE - jS;
    const u16* __restrict__ colp = hs + lane;

    int raw[32];
    #pragma unroll
    for (int i = 0; i < 32; ++i)
        raw[i] = __builtin_amdgcn_readfirstlane(csr_src[jS + i]);

    float acc = bf2f(colp[(size_t)node << 6]);   // self-loop
    u16 v[32];
    #pragma unroll
    for (int i = 0; i < 32; ++i) {
        int idx = (i < deg) ? raw[i] : N_NODES;
        v[i] = colp[(size_t)(unsigned)idx << 6];
    }
    #pragma unroll
    for (int i = 0; i < 32; ++i) acc += bf2f(v[i]);

    if (deg > 32) {
        for (int j = jS + 32; j < jE; ++j) {
            int idx = __builtin_amdgcn_readfirstlane(csr_src[j]);
            acc += bf2f(colp[(size_t)(unsigned)idx << 6]);
        }
    }

    out[((size_t)node << 6) + lane] = dinv[node] * acc + b[lane];
}

// ---------------------------------------------------------------- launch ----
extern "C" void kernel_launch(void* const* d_in, const int* in_sizes, int n_in,
                              void* d_out, int out_size, void* d_ws, size_t ws_size,
                              hipStream_t stream) {
    const float* x  = (const float*)d_in[0];
    const int* edge = (const int*)d_in[1];           // [2, N_EDGES] int32
    const float* W1 = (const float*)d_in[2];
    const float* b1 = (const float*)d_in[3];
    const float* W2 = (const float*)d_in[4];
    const float* b2 = (const float*)d_in[5];
    float* out = (float*)d_out;                      // [N_NODES, 64] fp32

    const int* src = edge;
    const int* dst = edge + N_EDGES;

    char* ws = (char*)d_ws;
    int*   bucketCursor = (int*)(ws);                 // 782 ints (pad 4096)
    int*   gBase        = (int*)(ws + 4096);          // 782 ints (pad 8192)
    int*   row_start    = (int*)(ws + 8192);          // N+1 (pad 408576)
    float* dinv         = (float*)(ws + 408576);      // N (pad 808960)
    int*   csr_src      = (int*)(ws + 808960);        // E + 32 slack (ends 7209088)
    u16*   hsb          = (u16*)(ws + 7209088);       // 100032*64 bf16 (ends 20013184)
    unsigned int* bins  = (unsigned int*)hsb;         // 8.13MB, dead before gemm1
    u16*   hsb2         = (u16*)(ws + 20013184);      // 100032*64 bf16 (ends 32817280)
    u16*   w1pre        = (u16*)(ws + 32817280);      // 32 KB (ends 32850048)
    u16*   w2pre        = (u16*)(ws + 32850048);      // 16 KB (ends 32866432)

    const int nBlkBin  = (N_EDGES + BINCHUNK - 1) / BINCHUNK;  // 391
    const int nBlkGemm = (N_NODES + 63) / 64;                  // 1563 (covers 100032)
    const int nBlkAgg  = N_NODES / 4;                          // 25000

    // ---- CSR build + weight pre-split ----
    hipMemsetAsync(bucketCursor, 0, NBUK * sizeof(int), stream);
    k_wsplit<<<1, 256, 0, stream>>>(W1, W2, w1pre, w2pre);
    k_bin<<<nBlkBin, 256, 0, stream>>>(src, dst, bucketCursor, bins);
    k_bscan<<<1, 256, 0, stream>>>(bucketCursor, gBase, row_start);
    k_build<<<NBUK, 256, 0, stream>>>(bins, bucketCursor, gBase, row_start, dinv, csr_src);

    // ---- layer 1 GEMM ----
    k_gemm1<<<nBlkGemm, 256, 0, stream>>>(x, w1pre, dinv, hsb);

    // ---- fused aggregate1 + GELU + GEMM2 ----
    k_agg1g2<<<nBlkGemm, 256, 0, stream>>>(hsb, csr_src, row_start, dinv, b1, w2pre, hsb2);

    // ---- final aggregate ----
    k_aggregate2<<<nBlkAgg, 256, 0, stream>>>(hsb2, csr_src, row_start, dinv, b2, out);
}

// Round 13
// 177.394 us; speedup vs baseline: 1.0807x; 1.0807x over previous
//
#include <hip/hip_runtime.h>
#include <math.h>

#define N_NODES 100000
#define N_EDGES 1600000
#define NBUK 782          // dst>>7 -> 0..781 (128 nodes per bucket)
#define BCAP 2600         // entries per bucket region (mean 2046)
#define BINCHUNK 4096     // edges per k_bin block (256 thr x 16)

typedef unsigned short u16;
typedef u16 u16x4 __attribute__((ext_vector_type(4)));
typedef u16 u16x8 __attribute__((ext_vector_type(8)));
typedef short s16x8 __attribute__((ext_vector_type(8)));
typedef float f32x4 __attribute__((ext_vector_type(4)));

__device__ __forceinline__ float bf2f(u16 u) {
    union { unsigned i; float f; } v; v.i = ((unsigned)u) << 16; return v.f;
}
__device__ __forceinline__ u16 f2bf(float f) {
    union { float f; unsigned i; } v; v.f = f;
    return (u16)((v.i + 0x7FFFu + ((v.i >> 16) & 1u)) >> 16);  // RNE
}

// ---------------------------------------------------------------- binning ---
__global__ __launch_bounds__(256) void k_bin(const int* __restrict__ src,
                                             const int* __restrict__ dst,
                                             int* bucketCursor,
                                             unsigned int* __restrict__ bins) {
    __shared__ int lcnt[NBUK];
    __shared__ int lbase[NBUK];
    const int t = threadIdx.x;
    for (int i = t; i < NBUK; i += 256) lcnt[i] = 0;
    __syncthreads();

    const int e0 = blockIdx.x * BINCHUNK + t * 16;
    int4 s4[4], d4[4];
    int bkt[16], rnk[16];
    const bool valid = e0 < N_EDGES;   // N_EDGES % 16 == 0
    if (valid) {
        #pragma unroll
        for (int k = 0; k < 4; ++k) {
            s4[k] = *(const int4*)(src + e0 + 4 * k);
            d4[k] = *(const int4*)(dst + e0 + 4 * k);
        }
        #pragma unroll
        for (int k = 0; k < 4; ++k) {
            int dd[4] = { d4[k].x, d4[k].y, d4[k].z, d4[k].w };
            #pragma unroll
            for (int j = 0; j < 4; ++j) {
                int b = dd[j] >> 7;
                bkt[4 * k + j] = b;
                rnk[4 * k + j] = atomicAdd(&lcnt[b], 1);
            }
        }
    }
    __syncthreads();
    for (int i = t; i < NBUK; i += 256)
        if (lcnt[i] > 0) lbase[i] = atomicAdd(&bucketCursor[i], lcnt[i]);
    __syncthreads();
    if (valid) {
        #pragma unroll
        for (int k = 0; k < 4; ++k) {
            int ss[4] = { s4[k].x, s4[k].y, s4[k].z, s4[k].w };
            int dd[4] = { d4[k].x, d4[k].y, d4[k].z, d4[k].w };
            #pragma unroll
            for (int j = 0; j < 4; ++j) {
                int i = 4 * k + j;
                unsigned w = ((unsigned)(dd[j] & 127) << 17) | (unsigned)ss[j];
                bins[(size_t)bkt[i] * BCAP + lbase[bkt[i]] + rnk[i]] = w;
            }
        }
    }
}

// ------------------------------------------------- bucket-total scan (1 wg) -
__global__ __launch_bounds__(256) void k_bscan(const int* __restrict__ bucketCursor,
                                               int* __restrict__ gBase,
                                               int* __restrict__ row_start) {
    __shared__ int sd[256];
    const int t = threadIdx.x;
    const int idx0 = t * 4;
    int v0 = (idx0 + 0 < NBUK) ? bucketCursor[idx0 + 0] : 0;
    int v1 = (idx0 + 1 < NBUK) ? bucketCursor[idx0 + 1] : 0;
    int v2 = (idx0 + 2 < NBUK) ? bucketCursor[idx0 + 2] : 0;
    int v3 = (idx0 + 3 < NBUK) ? bucketCursor[idx0 + 3] : 0;
    int s0 = v0, s1 = s0 + v1, s2 = s1 + v2, s3 = s2 + v3;
    sd[t] = s3;
    __syncthreads();
    #pragma unroll
    for (int off = 1; off < 256; off <<= 1) {
        int x = (t >= off) ? sd[t - off] : 0;
        __syncthreads();
        sd[t] += x;
        __syncthreads();
    }
    int excl = (t > 0) ? sd[t - 1] : 0;
    if (idx0 + 0 < NBUK) gBase[idx0 + 0] = excl;
    if (idx0 + 1 < NBUK) gBase[idx0 + 1] = excl + s0;
    if (idx0 + 2 < NBUK) gBase[idx0 + 2] = excl + s1;
    if (idx0 + 3 < NBUK) gBase[idx0 + 3] = excl + s2;
    if (t == 0) row_start[N_NODES] = N_EDGES;
}

// ------------------------------------------- per-bucket CSR build (128) -----
__global__ __launch_bounds__(256) void k_build(const unsigned int* __restrict__ bins,
                                               const int* __restrict__ bucketCursor,
                                               const int* __restrict__ gBase,
                                               int* __restrict__ row_start,
                                               float* __restrict__ dinv,
                                               int* __restrict__ csr_src) {
    __shared__ int cnt[128];
    __shared__ int ps[128];
    __shared__ int cur[128];
    const int b = blockIdx.x;
    const int t = threadIdx.x;
    const int bcnt = bucketCursor[b];
    const int gb = gBase[b];
    const unsigned int* mybins = bins + (size_t)b * BCAP;

    if (t < 128) cnt[t] = 0;
    __syncthreads();
    for (int i = t; i < bcnt; i += 256)
        atomicAdd(&cnt[mybins[i] >> 17], 1);
    __syncthreads();
    if (t < 128) ps[t] = cnt[t];
    __syncthreads();
    #pragma unroll
    for (int off = 1; off < 128; off <<= 1) {
        int x = (t >= off && t < 128) ? ps[t - off] : 0;
        __syncthreads();
        if (t < 128) ps[t] += x;
        __syncthreads();
    }
    if (t < 128) {
        int excl = (t > 0) ? ps[t - 1] : 0;
        cur[t] = excl;
        int node = (b << 7) + t;
        if (node < N_NODES) {
            row_start[node] = gb + excl;
            dinv[node] = rsqrtf((float)(cnt[t] + 1));
        }
    }
    __syncthreads();
    for (int i = t; i < bcnt; i += 256) {
        unsigned w = mybins[i];
        int dl = w >> 17;
        int s = (int)(w & 0x1FFFFu);
        int p = atomicAdd(&cur[dl], 1);
        csr_src[gb + p] = s;
    }
}

// --------------------------------------- W pre-split (transposed+swizzled) --
// w1pre: [hi 16KB][lo 16KB]  byte = (c*256 + k*2) ^ ((c&7)<<4)   (c<64,k<128)
// w2pre: [hi 8KB][lo 8KB]    byte = (c*128 + k*2) ^ ((c&7)<<4)   (c<64,k<64)
__global__ __launch_bounds__(256) void k_wsplit(const float* __restrict__ W1,
                                                const float* __restrict__ W2,
                                                u16* __restrict__ w1pre,
                                                u16* __restrict__ w2pre) {
    const int t = threadIdx.x;
    #pragma unroll
    for (int i = 0; i < 32; ++i) {
        int e = i * 256 + t;           // e = k*64 + c
        int k = e >> 6, c = e & 63;
        float f = W1[e];
        u16 h = f2bf(f);
        u16 l = f2bf(f - bf2f(h));
        int byte = (c * 256 + k * 2) ^ ((c & 7) << 4);
        *(u16*)((char*)w1pre + byte) = h;
        *(u16*)((char*)w1pre + 16384 + byte) = l;
    }
    #pragma unroll
    for (int i = 0; i < 16; ++i) {
        int e = i * 256 + t;
        int k = e >> 6, c = e & 63;
        float f = W2[e];
        u16 h = f2bf(f);
        u16 l = f2bf(f - bf2f(h));
        int byte = (c * 128 + k * 2) ^ ((c & 7) << 4);
        *(u16*)((char*)w2pre + byte) = h;
        *(u16*)((char*)w2pre + 8192 + byte) = l;
    }
}

// ------------------------------------------------------- GEMM1 (MFMA) -------
// C = (x @ W1) * dinv via hi/lo bf16 split; W1 pre-split in w1pre.
__global__ __launch_bounds__(256) void k_gemm1(const float* __restrict__ X,
                                               const u16* __restrict__ w1pre,
                                               const float* __restrict__ dinv,
                                               u16* __restrict__ H) {
    __shared__ u16 sxh[64 * 128];
    __shared__ u16 sxl[64 * 128];
    __shared__ u16 wth[64 * 128];
    __shared__ u16 wtl[64 * 128];
    const int t = threadIdx.x;
    const int blk = blockIdx.x;

    {   // stage x tile: 64 rows x 128 cols fp32 -> hi/lo bf16
        const float4* Xv = (const float4*)X;
        #pragma unroll
        for (int i = 0; i < 8; ++i) {
            int idx = i * 256 + t;
            int row = idx >> 5;
            int k4  = (idx & 31) << 2;
            int grow = blk * 64 + row;
            float4 v = make_float4(0.f, 0.f, 0.f, 0.f);
            if (grow < N_NODES) v = Xv[(size_t)grow * 32 + (idx & 31)];
            float f[4] = { v.x, v.y, v.z, v.w };
            u16x4 hv, lv;
            #pragma unroll
            for (int j = 0; j < 4; ++j) {
                u16 h = f2bf(f[j]);
                hv[j] = h;
                lv[j] = f2bf(f[j] - bf2f(h));
            }
            int byte = (row * 256 + k4 * 2) ^ ((row & 7) << 4);
            *(u16x4*)((char*)sxh + byte) = hv;
            *(u16x4*)((char*)sxl + byte) = lv;
        }
    }
    {   // stage pre-split W1: pure 16B copy (layout already swizzled)
        const u16x8* G = (const u16x8*)w1pre;
        u16x8* Lh = (u16x8*)wth;
        u16x8* Ll = (u16x8*)wtl;
        #pragma unroll
        for (int i = 0; i < 4; ++i) Lh[i * 256 + t] = G[i * 256 + t];
        #pragma unroll
        for (int i = 0; i < 4; ++i) Ll[i * 256 + t] = G[1024 + i * 256 + t];
    }
    __syncthreads();

    const int lane = t & 63;
    const int w    = t >> 6;
    const int l16  = lane & 15;
    const int kg   = lane >> 4;
    f32x4 acc[4];
    #pragma unroll
    for (int nt = 0; nt < 4; ++nt)
        #pragma unroll
        for (int j = 0; j < 4; ++j) acc[nt][j] = 0.f;

    const int arow = w * 16 + l16;
    const int aswz = (arow & 7) << 4;
    #pragma unroll
    for (int kt = 0; kt < 4; ++kt) {
        const int koff = kt * 64 + kg * 16;
        s16x8 ah = *(const s16x8*)((const char*)sxh + ((arow * 256 + koff) ^ aswz));
        s16x8 al = *(const s16x8*)((const char*)sxl + ((arow * 256 + koff) ^ aswz));
        #pragma unroll
        for (int nt = 0; nt < 4; ++nt) {
            const int c = nt * 16 + l16;
            const int wb = (c * 256 + koff) ^ ((c & 7) << 4);
            s16x8 bh = *(const s16x8*)((const char*)wth + wb);
            s16x8 bl = *(const s16x8*)((const char*)wtl + wb);
            acc[nt] = __builtin_amdgcn_mfma_f32_16x16x32_bf16(ah, bh, acc[nt], 0, 0, 0);
            acc[nt] = __builtin_amdgcn_mfma_f32_16x16x32_bf16(ah, bl, acc[nt], 0, 0, 0);
            acc[nt] = __builtin_amdgcn_mfma_f32_16x16x32_bf16(al, bh, acc[nt], 0, 0, 0);
        }
    }
    const int rbase = blk * 64 + w * 16 + kg * 4;
    #pragma unroll
    for (int reg = 0; reg < 4; ++reg) {
        int row = rbase + reg;
        float di = (row < N_NODES) ? dinv[row] : 0.f;
        #pragma unroll
        for (int nt = 0; nt < 4; ++nt)
            __builtin_nontemporal_store(f2bf(acc[nt][reg] * di),
                                        &H[(size_t)row * 64 + nt * 16 + l16]);
    }
}

// ------------------------------------------------------- GEMM2 (MFMA) -------
// Input already bf16 (exact); W2 pre-split in w2pre.
__global__ __launch_bounds__(256) void k_gemm2(const u16* __restrict__ Xb,
                                               const u16* __restrict__ w2pre,
                                               const float* __restrict__ dinv,
                                               u16* __restrict__ H) {
    __shared__ u16 sxb[64 * 64];
    __shared__ u16 wth[64 * 64];
    __shared__ u16 wtl[64 * 64];
    const int t = threadIdx.x;
    const int blk = blockIdx.x;

    {   // stage input tile 64x64 bf16
        const u16x8* Xv = (const u16x8*)Xb;
        #pragma unroll
        for (int i = 0; i < 2; ++i) {
            int idx = i * 256 + t;
            int row = idx >> 3;
            int k0  = (idx & 7) << 3;
            int grow = blk * 64 + row;
            u16x8 v;
            #pragma unroll
            for (int j = 0; j < 8; ++j) v[j] = 0;
            if (grow < N_NODES) v = Xv[(size_t)grow * 8 + (idx & 7)];
            int byte = (row * 128 + k0 * 2) ^ ((row & 7) << 4);
            *(u16x8*)((char*)sxb + byte) = v;
        }
    }
    {   // stage pre-split W2 (16 KB): pure copy
        const u16x8* G = (const u16x8*)w2pre;
        u16x8* Lh = (u16x8*)wth;
        u16x8* Ll = (u16x8*)wtl;
        #pragma unroll
        for (int i = 0; i < 2; ++i) Lh[i * 256 + t] = G[i * 256 + t];
        #pragma unroll
        for (int i = 0; i < 2; ++i) Ll[i * 256 + t] = G[512 + i * 256 + t];
    }
    __syncthreads();

    const int lane = t & 63;
    const int w    = t >> 6;
    const int l16  = lane & 15;
    const int kg   = lane >> 4;
    f32x4 acc[4];
    #pragma unroll
    for (int nt = 0; nt < 4; ++nt)
        #pragma unroll
        for (int j = 0; j < 4; ++j) acc[nt][j] = 0.f;

    const int arow = w * 16 + l16;
    const int aswz = (arow & 7) << 4;
    #pragma unroll
    for (int kt = 0; kt < 2; ++kt) {
        const int koff = kt * 64 + kg * 16;
        s16x8 a = *(const s16x8*)((const char*)sxb + ((arow * 128 + koff) ^ aswz));
        #pragma unroll
        for (int nt = 0; nt < 4; ++nt) {
            const int c = nt * 16 + l16;
            const int wb = (c * 128 + koff) ^ ((c & 7) << 4);
            s16x8 bh = *(const s16x8*)((const char*)wth + wb);
            s16x8 bl = *(const s16x8*)((const char*)wtl + wb);
            acc[nt] = __builtin_amdgcn_mfma_f32_16x16x32_bf16(a, bh, acc[nt], 0, 0, 0);
            acc[nt] = __builtin_amdgcn_mfma_f32_16x16x32_bf16(a, bl, acc[nt], 0, 0, 0);
        }
    }
    const int rbase = blk * 64 + w * 16 + kg * 4;
    #pragma unroll
    for (int reg = 0; reg < 4; ++reg) {
        int row = rbase + reg;
        float di = (row < N_NODES) ? dinv[row] : 0.f;
        #pragma unroll
        for (int nt = 0; nt < 4; ++nt)
            __builtin_nontemporal_store(f2bf(acc[nt][reg] * di),
                                        &H[(size_t)row * 64 + nt * 16 + l16]);
    }
}

// ---------------------------------------------------------------- aggregate -
// One wave per node, 4 independent waves/block, NO LDS, NO barriers (r11).
template <bool GELU>
__global__ __launch_bounds__(256) void k_aggregate(const u16* __restrict__ hs,
                                                   const int* __restrict__ csr_src,
                                                   const int* __restrict__ row_start,
                                                   const float* __restrict__ dinv,
                                                   const float* __restrict__ b,
                                                   void* __restrict__ outraw) {
    const int t = threadIdx.x;
    const int lane = t & 63;
    const int node = __builtin_amdgcn_readfirstlane(blockIdx.x * 4 + (t >> 6));
    const int jS = __builtin_amdgcn_readfirstlane(row_start[node]);
    const int jE = __builtin_amdgcn_readfirstlane(row_start[node + 1]);
    const int deg = jE - jS;
    const u16* __restrict__ colp = hs + lane;

    int raw[32];
    #pragma unroll
    for (int i = 0; i < 32; ++i)
        raw[i] = __builtin_amdgcn_readfirstlane(csr_src[jS + i]);

    float acc = bf2f(colp[(size_t)node << 6]);   // self-loop
    u16 v[32];
    #pragma unroll
    for (int i = 0; i < 32; ++i) {
        int idx = (i < deg) ? raw[i] : N_NODES;   // scalar select, branchless
        v[i] = colp[(size_t)(unsigned)idx << 6];
    }
    #pragma unroll
    for (int i = 0; i < 32; ++i) acc += bf2f(v[i]);

    if (deg > 32) {   // rare scalar tail
        for (int j = jS + 32; j < jE; ++j) {
            int idx = __builtin_amdgcn_readfirstlane(csr_src[j]);
            acc += bf2f(colp[(size_t)(unsigned)idx << 6]);
        }
    }

    float r = dinv[node] * acc + b[lane];
    if (GELU) {
        r = 0.5f * r * (1.0f + erff(r * 0.70710678118654752f));
        ((u16*)outraw)[((size_t)node << 6) + lane] = f2bf(r);
    } else {
        ((float*)outraw)[((size_t)node << 6) + lane] = r;
    }
}

// ---------------------------------------------------------------- launch ----
extern "C" void kernel_launch(void* const* d_in, const int* in_sizes, int n_in,
                              void* d_out, int out_size, void* d_ws, size_t ws_size,
                              hipStream_t stream) {
    const float* x  = (const float*)d_in[0];
    const int* edge = (const int*)d_in[1];           // [2, N_EDGES] int32
    const float* W1 = (const float*)d_in[2];
    const float* b1 = (const float*)d_in[3];
    const float* W2 = (const float*)d_in[4];
    const float* b2 = (const float*)d_in[5];
    float* out = (float*)d_out;                      // [N_NODES, 64] fp32

    const int* src = edge;
    const int* dst = edge + N_EDGES;

    char* ws = (char*)d_ws;
    int*   bucketCursor = (int*)(ws);                 // 782 ints (pad 4096)
    int*   gBase        = (int*)(ws + 4096);          // 782 ints (pad 8192)
    int*   row_start    = (int*)(ws + 8192);          // N+1 (pad 408576)
    float* dinv         = (float*)(ws + 408576);      // N (pad 808960)
    int*   csr_src      = (int*)(ws + 808960);        // E + 32 slack (ends 7209088)
    u16*   hsb          = (u16*)(ws + 7209088);       // 100032*64 bf16 (ends 20013184)
    unsigned int* bins  = (unsigned int*)hsb;         // 8.13MB, dead before gemm1
    u16*   out1b        = (u16*)(ws + 20013184);      // 100032*64 bf16 (ends 32817280)
    u16*   w1pre        = (u16*)(ws + 32817280);      // 32 KB (ends 32850048)
    u16*   w2pre        = (u16*)(ws + 32850048);      // 16 KB (ends 32866432)

    const int nBlkBin  = (N_EDGES + BINCHUNK - 1) / BINCHUNK;  // 391
    const int nBlkGemm = (N_NODES + 63) / 64;                  // 1563 (covers 100032)
    const int nBlkAgg  = N_NODES / 4;                          // 25000

    // ---- CSR build + weight pre-split ----
    hipMemsetAsync(bucketCursor, 0, NBUK * sizeof(int), stream);
    k_wsplit<<<1, 256, 0, stream>>>(W1, W2, w1pre, w2pre);
    k_bin<<<nBlkBin, 256, 0, stream>>>(src, dst, bucketCursor, bins);
    k_bscan<<<1, 256, 0, stream>>>(bucketCursor, gBase, row_start);
    k_build<<<NBUK, 256, 0, stream>>>(bins, bucketCursor, gBase, row_start, dinv, csr_src);

    // ---- layer 1 ----
    k_gemm1<<<nBlkGemm, 256, 0, stream>>>(x, w1pre, dinv, hsb);
    k_aggregate<true><<<nBlkAgg, 256, 0, stream>>>(hsb, csr_src, row_start, dinv, b1, out1b);

    // ---- layer 2 ----
    k_gemm2<<<nBlkGemm, 256, 0, stream>>>(out1b, w2pre, dinv, hsb);
    k_aggregate<false><<<nBlkAgg, 256, 0, stream>>>(hsb, csr_src, row_start, dinv, b2, out);
}